// Round 9
// baseline (192.735 us; speedup 1.0000x reference)
//
#include <hip/hip_runtime.h>
#include <hip/hip_bf16.h>
#include <math.h>

#define B_  8
#define C_  512
#define N_  1024
#define NH_ 8
#define HD_ 64
#define C3_ 1536

typedef __bf16 bf16x8  __attribute__((ext_vector_type(8)));
typedef __bf16 bf16x4v __attribute__((ext_vector_type(4)));
typedef short  s16x4   __attribute__((ext_vector_type(4)));
typedef float  f32x4   __attribute__((ext_vector_type(4)));
typedef __hip_bfloat16 bf16;

__device__ __forceinline__ f32x4 mfma16(const bf16x8& a, const bf16x8& b, const f32x4& c) {
    return __builtin_amdgcn_mfma_f32_16x16x32_bf16(a, b, c, 0, 0, 0);
}

// K=16 MFMA for the PV product: A,B are 4 bf16/lane (2 VGPRs).
__device__ __forceinline__ f32x4 mfma_pv(const bf16x4v& a, const bf16x4v& b, const f32x4& c) {
    return __builtin_amdgcn_mfma_f32_16x16x16bf16_1k(
        __builtin_bit_cast(s16x4, a), __builtin_bit_cast(s16x4, b), c, 0, 0, 0);
}

// async global->LDS, 16B per lane. LDS dest = wave-uniform base + lane*16.
__device__ __forceinline__ void ld_lds16(const bf16* g, bf16* l_uniform) {
    __builtin_amdgcn_global_load_lds(
        (const __attribute__((address_space(1))) void*)(uintptr_t)g,
        (__attribute__((address_space(3))) void*)(uintptr_t)l_uniform,
        16, 0, 0);
}

// ---------------- prep ----------------

__global__ __launch_bounds__(256) void cvt_w(const float* __restrict__ Wq,
                                             const float* __restrict__ Wp,
                                             bf16* __restrict__ Wqb,
                                             bf16* __restrict__ Wpb) {
    int i = blockIdx.x * 256 + threadIdx.x;
    if (i < C3_ * C_) Wqb[i] = __float2bfloat16(Wq[i]);
    else {
        int j = i - C3_ * C_;
        if (j < C_ * C_) Wpb[j] = __float2bfloat16(Wp[j]);
    }
}

// x (B, C, N) f32  ->  xb (B, N, C) bf16
__global__ __launch_bounds__(256) void transpose_x(const float* __restrict__ x,
                                                   bf16* __restrict__ xb) {
    __shared__ float T[32][33];
    const int n0 = blockIdx.x * 32, c0 = blockIdx.y * 32, b = blockIdx.z;
    const int tx = threadIdx.x, ty = threadIdx.y;
    const float* xp = x + ((size_t)b * C_ + c0) * N_ + n0;
#pragma unroll
    for (int l = 0; l < 4; ++l)
        T[ty + 8 * l][tx] = xp[(ty + 8 * l) * N_ + tx];
    __syncthreads();
    bf16* xo = xb + ((size_t)b * N_ + n0) * C_ + c0;
#pragma unroll
    for (int l = 0; l < 4; ++l)
        xo[(ty + 8 * l) * C_ + tx] = __float2bfloat16(T[tx][ty + 8 * l]);
}

// ---------------- QKV GEMM: 8192x1536x512, 128x128 tiles, LDS-staged ----------------
__global__ __launch_bounds__(256) void qkv_mfma(const bf16* __restrict__ xb,
                                                const bf16* __restrict__ Wqb,
                                                const float* __restrict__ bq,
                                                bf16* __restrict__ Qb,
                                                bf16* __restrict__ Kb,
                                                bf16* __restrict__ Vt) {
    __shared__ bf16 As[128 * 32];
    __shared__ bf16 Bs[128 * 32];
    __shared__ bf16 Vl[4][16][20];
    const int tid = threadIdx.x, w = tid >> 6, lane = tid & 63;
    const int lo = lane & 15, hi = lane >> 4;
    const int j0 = blockIdx.x * 128;
    const int m0 = blockIdx.y * 128;
    const int b  = m0 >> 10;

    const int srow = w * 32 + (lane >> 2);
    const int scol = (lane & 3) * 8;
    const bf16* gA = xb  + (size_t)(m0 + srow) * C_ + scol;
    const bf16* gB = Wqb + (size_t)(j0 + srow) * C_ + scol;
    bf16* lA = As + (w * 32) * 32;
    bf16* lB = Bs + (w * 32) * 32;

    f32x4 acc[4][4];
#pragma unroll
    for (int mt = 0; mt < 4; ++mt)
#pragma unroll
        for (int jt = 0; jt < 4; ++jt)
            acc[mt][jt] = (f32x4){0.f, 0.f, 0.f, 0.f};

    for (int k0 = 0; k0 < C_; k0 += 32) {
        ld_lds16(gA + k0, lA);
        ld_lds16(gA + (size_t)16 * C_ + k0, lA + 16 * 32);
        ld_lds16(gB + k0, lB);
        ld_lds16(gB + (size_t)16 * C_ + k0, lB + 16 * 32);
        __syncthreads();

        bf16x8 af[4], bfr[4];
#pragma unroll
        for (int mt = 0; mt < 4; ++mt)
            af[mt] = *(const bf16x8*)(As + ((w & 1) * 64 + mt * 16 + lo) * 32 + hi * 8);
#pragma unroll
        for (int jt = 0; jt < 4; ++jt)
            bfr[jt] = *(const bf16x8*)(Bs + ((w >> 1) * 64 + jt * 16 + lo) * 32 + hi * 8);
#pragma unroll
        for (int mt = 0; mt < 4; ++mt)
#pragma unroll
            for (int jt = 0; jt < 4; ++jt)
                acc[mt][jt] = mfma16(af[mt], bfr[jt], acc[mt][jt]);
        __syncthreads();
    }

    const int jb = (w >> 1) * 64;
    const int nbase = (m0 & 1023) + (w & 1) * 64;
#pragma unroll
    for (int jt = 0; jt < 4; ++jt) {
        const int j16 = j0 + jb + jt * 16;
        const float bias = bq[j16 + lo];
        if (j16 < 512) {
            const int h = j16 >> 6, d = (j16 & 63) + lo;
            bf16* qp = Qb + ((size_t)(b * NH_ + h) * N_) * HD_ + d;
#pragma unroll
            for (int mt = 0; mt < 4; ++mt)
#pragma unroll
                for (int r = 0; r < 4; ++r) {
                    int n = nbase + mt * 16 + hi * 4 + r;
                    qp[(size_t)n * HD_] = __float2bfloat16((acc[mt][jt][r] + bias) * 0.125f);
                }
        } else if (j16 < 1024) {
            const int jj = j16 - 512;
            const int h = jj >> 6, d = (jj & 63) + lo;
            bf16* kp = Kb + ((size_t)(b * NH_ + h) * N_) * HD_ + d;
#pragma unroll
            for (int mt = 0; mt < 4; ++mt)
#pragma unroll
                for (int r = 0; r < 4; ++r) {
                    int n = nbase + mt * 16 + hi * 4 + r;
                    kp[(size_t)n * HD_] = __float2bfloat16(acc[mt][jt][r] + bias);
                }
        } else {
            const int jj = j16 - 1024;
            const int h = jj >> 6, dbase = jj & 63;
            bf16* vp = Vt + ((size_t)(b * NH_ + h) * HD_ + dbase) * N_ + nbase;
#pragma unroll
            for (int mt = 0; mt < 4; ++mt) {
#pragma unroll
                for (int r = 0; r < 4; ++r)
                    Vl[w][hi * 4 + r][lo] = __float2bfloat16(acc[mt][jt][r] + bias);
#pragma unroll
                for (int r = 0; r < 4; ++r)
                    vp[(size_t)(hi * 4 + r) * N_ + mt * 16 + lo] = Vl[w][lo][hi * 4 + r];
            }
        }
    }
}

// ---------------- MFMA flash attention: S^T orientation, zero-LDS K-loop ----------------
// S^T = mfma(A=K_frag, B=Q_frag): output col=lane&15=q, row=quad*4+reg=key.
// exp(S^T) is then ALREADY in the B-operand layout of mfma_f32_16x16x16_bf16
// (B[k=quad*4+j][n=lane&15]), so PV is O^T += mfma16x16(A=V^T_frag, B=P) with
// no LDS round-trip, no shuffles, no barriers in the loop. L is a scalar/lane.
// Paired q-tiles (pi, 63-pi) keep the causal triangle balanced and share K/V loads.
// blockIdx = blk*64 + bh -> XCD = bh & 7 (per-XCD K/V working set ~3 MB in L2).

__global__ __launch_bounds__(256) void attn_mfma(const bf16* __restrict__ Qb,
                                                 const bf16* __restrict__ Kb,
                                                 const bf16* __restrict__ Vt,
                                                 bf16* __restrict__ ao) {
    __shared__ __bf16 Ot[4][16][72];             // epilogue transpose tile per wave
    const int wv   = threadIdx.x >> 6;
    const int lane = threadIdx.x & 63;
    const int lo   = lane & 15;
    const int hi   = lane >> 4;
    const int bh   = blockIdx.x & 63;            // XCD = bh & 7
    const int pi   = (blockIdx.x >> 6) * 4 + wv; // 0..31
    const int qwA  = pi * 16;
    const int qwB  = (63 - pi) * 16;

    const bf16* Qh = Qb + (size_t)bh * N_ * HD_;
    const bf16* Kh = Kb + (size_t)bh * N_ * HD_;
    const bf16* Vh = Vt + (size_t)bh * HD_ * N_;

    const bf16x8 qA0 = *(const bf16x8*)(Qh + (qwA + lo) * HD_ + hi * 8);
    const bf16x8 qA1 = *(const bf16x8*)(Qh + (qwA + lo) * HD_ + 32 + hi * 8);
    const bf16x8 qB0 = *(const bf16x8*)(Qh + (qwB + lo) * HD_ + hi * 8);
    const bf16x8 qB1 = *(const bf16x8*)(Qh + (qwB + lo) * HD_ + 32 + hi * 8);

    f32x4 OA[4], OB[4];                          // O^T: [d-tile], col=q, row=d_local
    float LAc = 0.f, LBc = 0.f;
#pragma unroll
    for (int t = 0; t < 4; ++t) {
        OA[t] = (f32x4){0.f, 0.f, 0.f, 0.f};
        OB[t] = (f32x4){0.f, 0.f, 0.f, 0.f};
    }

    const int nkbA = (qwA + 79) >> 6;            // 64-key blocks
    const int nkbB = (qwB + 79) >> 6;

    for (int kb = 0; kb < nkbB; ++kb) {
        const int key0 = kb * 64;
        const bool doA = (kb < nkbA);

        // K fragments: 4 key-subtiles x 2 d-halves (16B each)
        bf16x8 kf[4][2];
#pragma unroll
        for (int t = 0; t < 4; ++t) {
            const bf16* kp = Kh + (size_t)(key0 + t * 16 + lo) * HD_ + hi * 8;
            kf[t][0] = *(const bf16x8*)(kp);
            kf[t][1] = *(const bf16x8*)(kp + 32);
        }
        // V^T fragments for K=16 PV: 4 d-tiles x 4 key-subtiles (8B each)
        bf16x4v vf[4][4];
#pragma unroll
        for (int t = 0; t < 4; ++t) {
            const bf16* vp = Vh + (size_t)(t * 16 + lo) * N_ + key0 + 4 * hi;
#pragma unroll
            for (int s = 0; s < 4; ++s)
                vf[t][s] = *(const bf16x4v*)(vp + s * 16);
        }

        // S^T = K·Q^T (A=K, B=Q)
        f32x4 SB[4], SA[4];
#pragma unroll
        for (int t = 0; t < 4; ++t) {
            SB[t] = (f32x4){0.f, 0.f, 0.f, 0.f};
            SB[t] = mfma16(kf[t][0], qB0, SB[t]);
            SB[t] = mfma16(kf[t][1], qB1, SB[t]);
        }
        if (doA) {
#pragma unroll
            for (int t = 0; t < 4; ++t) {
                SA[t] = (f32x4){0.f, 0.f, 0.f, 0.f};
                SA[t] = mfma16(kf[t][0], qA0, SA[t]);
                SA[t] = mfma16(kf[t][1], qA1, SA[t]);
            }
        }

        // causal mask: key = key0 + t*16 + 4*hi + r, q = qw + lo
        if (key0 + 63 > qwB) {
#pragma unroll
            for (int t = 0; t < 4; ++t)
#pragma unroll
                for (int r = 0; r < 4; ++r)
                    if (key0 + t * 16 + 4 * hi + r > qwB + lo) SB[t][r] = -1e30f;
        }
        if (doA && key0 + 63 > qwA) {
#pragma unroll
            for (int t = 0; t < 4; ++t)
#pragma unroll
                for (int r = 0; r < 4; ++r)
                    if (key0 + t * 16 + 4 * hi + r > qwA + lo) SA[t][r] = -1e30f;
        }

        // exp + pack to bf16 (stays in registers, already B-layout for K=16 MFMA)
        bf16x4v pB[4], pA[4];
#pragma unroll
        for (int t = 0; t < 4; ++t)
#pragma unroll
            for (int r = 0; r < 4; ++r) {
                float p = __expf(SB[t][r]);
                LBc += p;
                pB[t][r] = (__bf16)p;
            }
        if (doA) {
#pragma unroll
            for (int t = 0; t < 4; ++t)
#pragma unroll
                for (int r = 0; r < 4; ++r) {
                    float p = __expf(SA[t][r]);
                    LAc += p;
                    pA[t][r] = (__bf16)p;
                }
        }

        // O^T += V^T·P^T  (t = d-tile, s = key-subtile)
#pragma unroll
        for (int t = 0; t < 4; ++t)
#pragma unroll
            for (int s = 0; s < 4; ++s)
                OB[t] = mfma_pv(vf[t][s], pB[s], OB[t]);
        if (doA) {
#pragma unroll
            for (int t = 0; t < 4; ++t)
#pragma unroll
                for (int s = 0; s < 4; ++s)
                    OA[t] = mfma_pv(vf[t][s], pA[s], OA[t]);
        }
    }

    // epilogue: L-reduce (2 shuffles), scale, LDS transpose, coalesced store
    const int b = bh >> 3, h = bh & 7;
#pragma unroll
    for (int c = 0; c < 2; ++c) {
        const int qw = c ? qwB : qwA;
        f32x4* O = c ? OB : OA;
        float Lc = c ? LBc : LAc;
        Lc += __shfl_xor(Lc, 16, 64);
        Lc += __shfl_xor(Lc, 32, 64);
        const float rL = 1.f / Lc;
#pragma unroll
        for (int t = 0; t < 4; ++t)
#pragma unroll
            for (int r = 0; r < 4; ++r)
                Ot[wv][lo][t * 16 + 4 * hi + r] = (__bf16)(O[t][r] * rL);
        // same-wave DS ops complete in order; compiler inserts the lgkm wait
#pragma unroll
        for (int p = 0; p < 4; ++p) {
            const int q = p * 4 + hi;
            bf16x4v o4 = *(const bf16x4v*)(&Ot[wv][q][lo * 4]);
            *(bf16x4v*)(ao + ((size_t)b * N_ + qw + q) * C_ + h * HD_ + lo * 4) = o4;
        }
    }
}

// ---------------- Projection GEMM: 512x8192x512, 64j x 128n tiles, LDS-staged ----------------
__global__ __launch_bounds__(256) void proj_mfma(const bf16* __restrict__ aob,
                                                 const bf16* __restrict__ Wpb,
                                                 const float* __restrict__ bp,
                                                 float* __restrict__ out) {
    __shared__ bf16 As[64 * 32];
    __shared__ bf16 Bs[128 * 32];
    const int tid = threadIdx.x, w = tid >> 6, lane = tid & 63;
    const int lo = lane & 15, hi = lane >> 4;
    const int j0 = blockIdx.x * 64;
    const int n0 = blockIdx.y * 128;
    const int b  = n0 >> 10;

    const int r4 = lane >> 2, c8 = (lane & 3) * 8;
    const bf16* gA = Wpb + (size_t)(j0 + w * 16 + r4) * C_ + c8;
    const bf16* gB = aob + (size_t)(n0 + w * 32 + r4) * C_ + c8;
    bf16* lA = As + (w * 16) * 32;
    bf16* lB = Bs + (w * 32) * 32;

    f32x4 acc[2][4];
#pragma unroll
    for (int mt = 0; mt < 2; ++mt)
#pragma unroll
        for (int jt = 0; jt < 4; ++jt)
            acc[mt][jt] = (f32x4){0.f, 0.f, 0.f, 0.f};

    for (int k0 = 0; k0 < C_; k0 += 32) {
        ld_lds16(gA + k0, lA);
        ld_lds16(gB + k0, lB);
        ld_lds16(gB + (size_t)16 * C_ + k0, lB + 16 * 32);
        __syncthreads();

        bf16x8 af[2], bfr[4];
#pragma unroll
        for (int mt = 0; mt < 2; ++mt)
            af[mt] = *(const bf16x8*)(As + ((w & 1) * 32 + mt * 16 + lo) * 32 + hi * 8);
#pragma unroll
        for (int jt = 0; jt < 4; ++jt)
            bfr[jt] = *(const bf16x8*)(Bs + ((w >> 1) * 64 + jt * 16 + lo) * 32 + hi * 8);
#pragma unroll
        for (int mt = 0; mt < 2; ++mt)
#pragma unroll
            for (int jt = 0; jt < 4; ++jt)
                acc[mt][jt] = mfma16(af[mt], bfr[jt], acc[mt][jt]);
        __syncthreads();
    }

#pragma unroll
    for (int mt = 0; mt < 2; ++mt)
#pragma unroll
        for (int r = 0; r < 4; ++r) {
            const int j = j0 + (w & 1) * 32 + mt * 16 + hi * 4 + r;
            const float bias = bp[j];
            float* op = out + ((size_t)(b * C_ + j)) * N_ + (n0 & 1023) + (w >> 1) * 64 + lo;
#pragma unroll
            for (int jt = 0; jt < 4; ++jt)
                op[jt * 16] = acc[mt][jt][r] + bias;
        }
}

extern "C" void kernel_launch(void* const* d_in, const int* in_sizes, int n_in,
                              void* d_out, int out_size, void* d_ws, size_t ws_size,
                              hipStream_t stream) {
    const float* x  = (const float*)d_in[0];
    const float* Wq = (const float*)d_in[1];
    const float* bq = (const float*)d_in[2];
    const float* Wp = (const float*)d_in[3];
    const float* bp = (const float*)d_in[4];
    float* out = (float*)d_out;

    const size_t headElems = (size_t)B_ * NH_ * N_ * HD_;
    bf16* xb  = (bf16*)d_ws;
    bf16* Wqb = xb + (size_t)B_ * N_ * C_;
    bf16* Wpb = Wqb + (size_t)C3_ * C_;
    bf16* Qb  = Wpb + (size_t)C_ * C_;
    bf16* Kb  = Qb + headElems;
    bf16* Vt  = Kb + headElems;
    bf16* aob = Vt + headElems;

    cvt_w<<<dim3((C3_ * C_ + C_ * C_ + 255) / 256), dim3(256), 0, stream>>>(Wq, Wp, Wqb, Wpb);
    transpose_x<<<dim3(N_ / 32, C_ / 32, B_), dim3(32, 8), 0, stream>>>(x, xb);

    qkv_mfma<<<dim3(C3_ / 128, (B_ * N_) / 128), dim3(256), 0, stream>>>(xb, Wqb, bq, Qb, Kb, Vt);
    attn_mfma<<<dim3(8 * 64), dim3(256), 0, stream>>>(Qb, Kb, Vt, aob);
    proj_mfma<<<dim3(C_ / 64, (B_ * N_) / 128), dim3(256), 0, stream>>>(aob, Wpb, bp, out);
}

// Round 10
// 182.339 us; speedup vs baseline: 1.0570x; 1.0570x over previous
//
#include <hip/hip_runtime.h>
#include <hip/hip_bf16.h>
#include <math.h>

#define B_  8
#define C_  512
#define N_  1024
#define NH_ 8
#define HD_ 64
#define C3_ 1536

typedef __bf16 bf16x8 __attribute__((ext_vector_type(8)));
typedef float  f32x4  __attribute__((ext_vector_type(4)));
typedef __hip_bfloat16 bf16;

__device__ __forceinline__ f32x4 mfma16(const bf16x8& a, const bf16x8& b, const f32x4& c) {
    return __builtin_amdgcn_mfma_f32_16x16x32_bf16(a, b, c, 0, 0, 0);
}

// async global->LDS, 16B per lane. LDS dest = wave-uniform base + lane*16.
__device__ __forceinline__ void ld_lds16(const bf16* g, bf16* l_uniform) {
    __builtin_amdgcn_global_load_lds(
        (const __attribute__((address_space(1))) void*)(uintptr_t)g,
        (__attribute__((address_space(3))) void*)(uintptr_t)l_uniform,
        16, 0, 0);
}

// ---------------- prep ----------------

__global__ __launch_bounds__(256) void cvt_w(const float* __restrict__ Wq,
                                             const float* __restrict__ Wp,
                                             bf16* __restrict__ Wqb,
                                             bf16* __restrict__ Wpb) {
    int i = blockIdx.x * 256 + threadIdx.x;
    if (i < C3_ * C_) Wqb[i] = __float2bfloat16(Wq[i]);
    else {
        int j = i - C3_ * C_;
        if (j < C_ * C_) Wpb[j] = __float2bfloat16(Wp[j]);
    }
}

// x (B, C, N) f32  ->  xb (B, N, C) bf16
__global__ __launch_bounds__(256) void transpose_x(const float* __restrict__ x,
                                                   bf16* __restrict__ xb) {
    __shared__ float T[32][33];
    const int n0 = blockIdx.x * 32, c0 = blockIdx.y * 32, b = blockIdx.z;
    const int tx = threadIdx.x, ty = threadIdx.y;
    const float* xp = x + ((size_t)b * C_ + c0) * N_ + n0;
#pragma unroll
    for (int l = 0; l < 4; ++l)
        T[ty + 8 * l][tx] = xp[(ty + 8 * l) * N_ + tx];
    __syncthreads();
    bf16* xo = xb + ((size_t)b * N_ + n0) * C_ + c0;
#pragma unroll
    for (int l = 0; l < 4; ++l)
        xo[(ty + 8 * l) * C_ + tx] = __float2bfloat16(T[tx][ty + 8 * l]);
}

// ---------------- QKV GEMM: 8192x1536x512, 128x128 tiles, LDS-staged ----------------
__global__ __launch_bounds__(256) void qkv_mfma(const bf16* __restrict__ xb,
                                                const bf16* __restrict__ Wqb,
                                                const float* __restrict__ bq,
                                                bf16* __restrict__ Qb,
                                                bf16* __restrict__ Kb,
                                                bf16* __restrict__ Vt) {
    __shared__ bf16 As[128 * 32];
    __shared__ bf16 Bs[128 * 32];
    __shared__ bf16 Vl[4][16][20];
    const int tid = threadIdx.x, w = tid >> 6, lane = tid & 63;
    const int lo = lane & 15, hi = lane >> 4;
    const int j0 = blockIdx.x * 128;
    const int m0 = blockIdx.y * 128;
    const int b  = m0 >> 10;

    const int srow = w * 32 + (lane >> 2);
    const int scol = (lane & 3) * 8;
    const bf16* gA = xb  + (size_t)(m0 + srow) * C_ + scol;
    const bf16* gB = Wqb + (size_t)(j0 + srow) * C_ + scol;
    bf16* lA = As + (w * 32) * 32;
    bf16* lB = Bs + (w * 32) * 32;

    f32x4 acc[4][4];
#pragma unroll
    for (int mt = 0; mt < 4; ++mt)
#pragma unroll
        for (int jt = 0; jt < 4; ++jt)
            acc[mt][jt] = (f32x4){0.f, 0.f, 0.f, 0.f};

    for (int k0 = 0; k0 < C_; k0 += 32) {
        ld_lds16(gA + k0, lA);
        ld_lds16(gA + (size_t)16 * C_ + k0, lA + 16 * 32);
        ld_lds16(gB + k0, lB);
        ld_lds16(gB + (size_t)16 * C_ + k0, lB + 16 * 32);
        __syncthreads();

        bf16x8 af[4], bfr[4];
#pragma unroll
        for (int mt = 0; mt < 4; ++mt)
            af[mt] = *(const bf16x8*)(As + ((w & 1) * 64 + mt * 16 + lo) * 32 + hi * 8);
#pragma unroll
        for (int jt = 0; jt < 4; ++jt)
            bfr[jt] = *(const bf16x8*)(Bs + ((w >> 1) * 64 + jt * 16 + lo) * 32 + hi * 8);
#pragma unroll
        for (int mt = 0; mt < 4; ++mt)
#pragma unroll
            for (int jt = 0; jt < 4; ++jt)
                acc[mt][jt] = mfma16(af[mt], bfr[jt], acc[mt][jt]);
        __syncthreads();
    }

    const int jb = (w >> 1) * 64;
    const int nbase = (m0 & 1023) + (w & 1) * 64;
#pragma unroll
    for (int jt = 0; jt < 4; ++jt) {
        const int j16 = j0 + jb + jt * 16;
        const float bias = bq[j16 + lo];
        if (j16 < 512) {
            const int h = j16 >> 6, d = (j16 & 63) + lo;
            bf16* qp = Qb + ((size_t)(b * NH_ + h) * N_) * HD_ + d;
#pragma unroll
            for (int mt = 0; mt < 4; ++mt)
#pragma unroll
                for (int r = 0; r < 4; ++r) {
                    int n = nbase + mt * 16 + hi * 4 + r;
                    qp[(size_t)n * HD_] = __float2bfloat16((acc[mt][jt][r] + bias) * 0.125f);
                }
        } else if (j16 < 1024) {
            const int jj = j16 - 512;
            const int h = jj >> 6, d = (jj & 63) + lo;
            bf16* kp = Kb + ((size_t)(b * NH_ + h) * N_) * HD_ + d;
#pragma unroll
            for (int mt = 0; mt < 4; ++mt)
#pragma unroll
                for (int r = 0; r < 4; ++r) {
                    int n = nbase + mt * 16 + hi * 4 + r;
                    kp[(size_t)n * HD_] = __float2bfloat16(acc[mt][jt][r] + bias);
                }
        } else {
            const int jj = j16 - 1024;
            const int h = jj >> 6, dbase = jj & 63;
            bf16* vp = Vt + ((size_t)(b * NH_ + h) * HD_ + dbase) * N_ + nbase;
#pragma unroll
            for (int mt = 0; mt < 4; ++mt) {
#pragma unroll
                for (int r = 0; r < 4; ++r)
                    Vl[w][hi * 4 + r][lo] = __float2bfloat16(acc[mt][jt][r] + bias);
#pragma unroll
                for (int r = 0; r < 4; ++r)
                    vp[(size_t)(hi * 4 + r) * N_ + mt * 16 + lo] = Vl[w][lo][hi * 4 + r];
            }
        }
    }
}

// ---------------- MFMA flash attention: one wave per q-tile, 4 waves/SIMD ----------------
// R6's proven per-iter chain (32 keys/iter, LDS P-transpose, no-max linear softmax),
// un-paired for 2x wave concurrency: 4096 waves in 1024 blocks (4 blocks/CU).
// Block group g (0..15): wave w owns q-tile g + 16*w -> per-block work uniform.
// blockIdx = g*64 + bh -> XCD = bh & 7 (each XCD sees 8 heads, ~3 MB L2 set).

__device__ __forceinline__ void attn_chain(
    const bf16x8& q0, const bf16x8& q1,
    const bf16x8& k00, const bf16x8& k01, const bf16x8& k10, const bf16x8& k11,
    const bf16x8& v0, const bf16x8& v1, const bf16x8& v2, const bf16x8& v3,
    int qw, int key0, int lo, int hi,
    bf16 (*pl)[40], f32x4* O, float* Lp)
{
    f32x4 S0 = {0.f, 0.f, 0.f, 0.f};
    f32x4 S1 = {0.f, 0.f, 0.f, 0.f};
    S0 = mfma16(q0, k00, S0);
    S0 = mfma16(q1, k01, S0);
    S1 = mfma16(q0, k10, S1);
    S1 = mfma16(q1, k11, S1);

    if (key0 + 31 > qw) {
#pragma unroll
        for (int r = 0; r < 4; ++r) {
            int q = qw + hi * 4 + r;
            if (key0 + lo > q)      S0[r] = -1e30f;
            if (key0 + 16 + lo > q) S1[r] = -1e30f;
        }
    }

#pragma unroll
    for (int r = 0; r < 4; ++r) {
        float p0 = __expf(S0[r]);
        float p1 = __expf(S1[r]);
        Lp[r] += p0 + p1;
        pl[hi * 4 + r][lo]      = __float2bfloat16(p0);
        pl[hi * 4 + r][16 + lo] = __float2bfloat16(p1);
    }

    bf16x8 pa = *(const bf16x8*)(&pl[lo][hi * 8]);
    O[0] = mfma16(pa, v0, O[0]);
    O[1] = mfma16(pa, v1, O[1]);
    O[2] = mfma16(pa, v2, O[2]);
    O[3] = mfma16(pa, v3, O[3]);
}

__global__ __launch_bounds__(256) void attn_mfma(const bf16* __restrict__ Qb,
                                                 const bf16* __restrict__ Kb,
                                                 const bf16* __restrict__ Vt,
                                                 bf16* __restrict__ ao) {
    __shared__ __align__(16) bf16 Pl[4][16][40];
    const int wv   = threadIdx.x >> 6;
    const int lane = threadIdx.x & 63;
    const int lo   = lane & 15;
    const int hi   = lane >> 4;
    const int bh   = blockIdx.x & 63;            // XCD = bh & 7
    const int g    = blockIdx.x >> 6;            // 0..15
    const int qt   = g + 16 * wv;                // spread assignment: block work uniform
    const int qw   = qt * 16;

    const bf16* Qh = Qb + (size_t)bh * N_ * HD_;
    const bf16* Kh = Kb + (size_t)bh * N_ * HD_;
    const bf16* Vh = Vt + (size_t)bh * HD_ * N_;

    const bf16x8 q0 = *(const bf16x8*)(Qh + (qw + lo) * HD_ + hi * 8);
    const bf16x8 q1 = *(const bf16x8*)(Qh + (qw + lo) * HD_ + 32 + hi * 8);

    f32x4 O[4];
    float Lp[4];
#pragma unroll
    for (int r = 0; r < 4; ++r) {
        O[0][r] = O[1][r] = O[2][r] = O[3][r] = 0.f;
        Lp[r] = 0.f;
    }

    const int nkb = (qw + 47) >> 5;              // 32-key blocks covering 0..qw+15
    for (int kb = 0; kb < nkb; ++kb) {
        const int key0 = kb * 32;
        const bf16* kp = Kh + (size_t)(key0 + lo) * HD_ + hi * 8;
        bf16x8 k00 = *(const bf16x8*)(kp);
        bf16x8 k01 = *(const bf16x8*)(kp + 32);
        bf16x8 k10 = *(const bf16x8*)(kp + 16 * HD_);
        bf16x8 k11 = *(const bf16x8*)(kp + 16 * HD_ + 32);
        const bf16* vp = Vh + (size_t)lo * N_ + key0 + hi * 8;
        bf16x8 v0 = *(const bf16x8*)(vp);
        bf16x8 v1 = *(const bf16x8*)(vp + 16 * N_);
        bf16x8 v2 = *(const bf16x8*)(vp + 32 * N_);
        bf16x8 v3 = *(const bf16x8*)(vp + 48 * N_);

        attn_chain(q0, q1, k00, k01, k10, k11, v0, v1, v2, v3,
                   qw, key0, lo, hi, Pl[wv], O, Lp);
    }

    const int b = bh >> 3, h = bh & 7;
    float rL[4];
#pragma unroll
    for (int r = 0; r < 4; ++r) {
        float Ls = Lp[r];
#pragma unroll
        for (int off = 1; off < 16; off <<= 1)
            Ls += __shfl_xor(Ls, off, 64);
        rL[r] = 1.f / Ls;
    }
#pragma unroll
    for (int t = 0; t < 4; ++t)
#pragma unroll
        for (int r = 0; r < 4; ++r) {
            int q = qw + hi * 4 + r;
            ao[((size_t)b * N_ + q) * C_ + h * HD_ + t * 16 + lo] =
                __float2bfloat16(O[t][r] * rL[r]);
        }
}

// ---------------- Projection GEMM: 512x8192x512, 64j x 128n tiles, LDS-staged ----------------
__global__ __launch_bounds__(256) void proj_mfma(const bf16* __restrict__ aob,
                                                 const bf16* __restrict__ Wpb,
                                                 const float* __restrict__ bp,
                                                 float* __restrict__ out) {
    __shared__ bf16 As[64 * 32];
    __shared__ bf16 Bs[128 * 32];
    const int tid = threadIdx.x, w = tid >> 6, lane = tid & 63;
    const int lo = lane & 15, hi = lane >> 4;
    const int j0 = blockIdx.x * 64;
    const int n0 = blockIdx.y * 128;
    const int b  = n0 >> 10;

    const int r4 = lane >> 2, c8 = (lane & 3) * 8;
    const bf16* gA = Wpb + (size_t)(j0 + w * 16 + r4) * C_ + c8;
    const bf16* gB = aob + (size_t)(n0 + w * 32 + r4) * C_ + c8;
    bf16* lA = As + (w * 16) * 32;
    bf16* lB = Bs + (w * 32) * 32;

    f32x4 acc[2][4];
#pragma unroll
    for (int mt = 0; mt < 2; ++mt)
#pragma unroll
        for (int jt = 0; jt < 4; ++jt)
            acc[mt][jt] = (f32x4){0.f, 0.f, 0.f, 0.f};

    for (int k0 = 0; k0 < C_; k0 += 32) {
        ld_lds16(gA + k0, lA);
        ld_lds16(gB + k0, lB);
        ld_lds16(gB + (size_t)16 * C_ + k0, lB + 16 * 32);
        __syncthreads();

        bf16x8 af[2], bfr[4];
#pragma unroll
        for (int mt = 0; mt < 2; ++mt)
            af[mt] = *(const bf16x8*)(As + ((w & 1) * 32 + mt * 16 + lo) * 32 + hi * 8);
#pragma unroll
        for (int jt = 0; jt < 4; ++jt)
            bfr[jt] = *(const bf16x8*)(Bs + ((w >> 1) * 64 + jt * 16 + lo) * 32 + hi * 8);
#pragma unroll
        for (int mt = 0; mt < 2; ++mt)
#pragma unroll
            for (int jt = 0; jt < 4; ++jt)
                acc[mt][jt] = mfma16(af[mt], bfr[jt], acc[mt][jt]);
        __syncthreads();
    }

#pragma unroll
    for (int mt = 0; mt < 2; ++mt)
#pragma unroll
        for (int r = 0; r < 4; ++r) {
            const int j = j0 + (w & 1) * 32 + mt * 16 + hi * 4 + r;
            const float bias = bp[j];
            float* op = out + ((size_t)(b * C_ + j)) * N_ + (n0 & 1023) + (w >> 1) * 64 + lo;
#pragma unroll
            for (int jt = 0; jt < 4; ++jt)
                op[jt * 16] = acc[mt][jt][r] + bias;
        }
}

extern "C" void kernel_launch(void* const* d_in, const int* in_sizes, int n_in,
                              void* d_out, int out_size, void* d_ws, size_t ws_size,
                              hipStream_t stream) {
    const float* x  = (const float*)d_in[0];
    const float* Wq = (const float*)d_in[1];
    const float* bq = (const float*)d_in[2];
    const float* Wp = (const float*)d_in[3];
    const float* bp = (const float*)d_in[4];
    float* out = (float*)d_out;

    const size_t headElems = (size_t)B_ * NH_ * N_ * HD_;
    bf16* xb  = (bf16*)d_ws;
    bf16* Wqb = xb + (size_t)B_ * N_ * C_;
    bf16* Wpb = Wqb + (size_t)C3_ * C_;
    bf16* Qb  = Wpb + (size_t)C_ * C_;
    bf16* Kb  = Qb + headElems;
    bf16* Vt  = Kb + headElems;
    bf16* aob = Vt + headElems;

    cvt_w<<<dim3((C3_ * C_ + C_ * C_ + 255) / 256), dim3(256), 0, stream>>>(Wq, Wp, Wqb, Wpb);
    transpose_x<<<dim3(N_ / 32, C_ / 32, B_), dim3(32, 8), 0, stream>>>(x, xb);

    qkv_mfma<<<dim3(C3_ / 128, (B_ * N_) / 128), dim3(256), 0, stream>>>(xb, Wqb, bq, Qb, Kb, Vt);
    attn_mfma<<<dim3(16 * 64), dim3(256), 0, stream>>>(Qb, Kb, Vt, aob);
    proj_mfma<<<dim3(C_ / 64, (B_ * N_) / 128), dim3(256), 0, stream>>>(aob, Wpb, bp, out);
}

// Round 11
// 169.590 us; speedup vs baseline: 1.1365x; 1.0752x over previous
//
#include <hip/hip_runtime.h>
#include <hip/hip_bf16.h>
#include <math.h>

#define B_  8
#define C_  512
#define N_  1024
#define NH_ 8
#define HD_ 64
#define C3_ 1536

typedef __bf16 bf16x8 __attribute__((ext_vector_type(8)));
typedef float  f32x4  __attribute__((ext_vector_type(4)));
typedef __hip_bfloat16 bf16;

__device__ __forceinline__ f32x4 mfma16(const bf16x8& a, const bf16x8& b, const f32x4& c) {
    return __builtin_amdgcn_mfma_f32_16x16x32_bf16(a, b, c, 0, 0, 0);
}

// async global->LDS, 16B per lane. LDS dest = wave-uniform base + lane*16.
__device__ __forceinline__ void ld_lds16(const bf16* g, bf16* l_uniform) {
    __builtin_amdgcn_global_load_lds(
        (const __attribute__((address_space(1))) void*)(uintptr_t)g,
        (__attribute__((address_space(3))) void*)(uintptr_t)l_uniform,
        16, 0, 0);
}

// ---------------- prep ----------------

__global__ __launch_bounds__(256) void cvt_w(const float* __restrict__ Wq,
                                             const float* __restrict__ Wp,
                                             bf16* __restrict__ Wqb,
                                             bf16* __restrict__ Wpb) {
    int i = blockIdx.x * 256 + threadIdx.x;
    if (i < C3_ * C_) Wqb[i] = __float2bfloat16(Wq[i]);
    else {
        int j = i - C3_ * C_;
        if (j < C_ * C_) Wpb[j] = __float2bfloat16(Wp[j]);
    }
}

// x (B, C, N) f32  ->  xb (B, N, C) bf16
__global__ __launch_bounds__(256) void transpose_x(const float* __restrict__ x,
                                                   bf16* __restrict__ xb) {
    __shared__ float T[32][33];
    const int n0 = blockIdx.x * 32, c0 = blockIdx.y * 32, b = blockIdx.z;
    const int tx = threadIdx.x, ty = threadIdx.y;
    const float* xp = x + ((size_t)b * C_ + c0) * N_ + n0;
#pragma unroll
    for (int l = 0; l < 4; ++l)
        T[ty + 8 * l][tx] = xp[(ty + 8 * l) * N_ + tx];
    __syncthreads();
    bf16* xo = xb + ((size_t)b * N_ + n0) * C_ + c0;
#pragma unroll
    for (int l = 0; l < 4; ++l)
        xo[(ty + 8 * l) * C_ + tx] = __float2bfloat16(T[tx][ty + 8 * l]);
}

// ---------------- QKV GEMM: 8192x1536x512, 128x128 tiles, LDS-staged ----------------
__global__ __launch_bounds__(256) void qkv_mfma(const bf16* __restrict__ xb,
                                                const bf16* __restrict__ Wqb,
                                                const float* __restrict__ bq,
                                                bf16* __restrict__ Qb,
                                                bf16* __restrict__ Kb,
                                                bf16* __restrict__ Vt) {
    __shared__ bf16 As[128 * 32];
    __shared__ bf16 Bs[128 * 32];
    __shared__ bf16 Vl[4][16][20];
    const int tid = threadIdx.x, w = tid >> 6, lane = tid & 63;
    const int lo = lane & 15, hi = lane >> 4;
    const int j0 = blockIdx.x * 128;
    const int m0 = blockIdx.y * 128;
    const int b  = m0 >> 10;

    const int srow = w * 32 + (lane >> 2);
    const int scol = (lane & 3) * 8;
    const bf16* gA = xb  + (size_t)(m0 + srow) * C_ + scol;
    const bf16* gB = Wqb + (size_t)(j0 + srow) * C_ + scol;
    bf16* lA = As + (w * 32) * 32;
    bf16* lB = Bs + (w * 32) * 32;

    f32x4 acc[4][4];
#pragma unroll
    for (int mt = 0; mt < 4; ++mt)
#pragma unroll
        for (int jt = 0; jt < 4; ++jt)
            acc[mt][jt] = (f32x4){0.f, 0.f, 0.f, 0.f};

    for (int k0 = 0; k0 < C_; k0 += 32) {
        ld_lds16(gA + k0, lA);
        ld_lds16(gA + (size_t)16 * C_ + k0, lA + 16 * 32);
        ld_lds16(gB + k0, lB);
        ld_lds16(gB + (size_t)16 * C_ + k0, lB + 16 * 32);
        __syncthreads();

        bf16x8 af[4], bfr[4];
#pragma unroll
        for (int mt = 0; mt < 4; ++mt)
            af[mt] = *(const bf16x8*)(As + ((w & 1) * 64 + mt * 16 + lo) * 32 + hi * 8);
#pragma unroll
        for (int jt = 0; jt < 4; ++jt)
            bfr[jt] = *(const bf16x8*)(Bs + ((w >> 1) * 64 + jt * 16 + lo) * 32 + hi * 8);
#pragma unroll
        for (int mt = 0; mt < 4; ++mt)
#pragma unroll
            for (int jt = 0; jt < 4; ++jt)
                acc[mt][jt] = mfma16(af[mt], bfr[jt], acc[mt][jt]);
        __syncthreads();
    }

    const int jb = (w >> 1) * 64;
    const int nbase = (m0 & 1023) + (w & 1) * 64;
#pragma unroll
    for (int jt = 0; jt < 4; ++jt) {
        const int j16 = j0 + jb + jt * 16;
        const float bias = bq[j16 + lo];
        if (j16 < 512) {
            const int h = j16 >> 6, d = (j16 & 63) + lo;
            bf16* qp = Qb + ((size_t)(b * NH_ + h) * N_) * HD_ + d;
#pragma unroll
            for (int mt = 0; mt < 4; ++mt)
#pragma unroll
                for (int r = 0; r < 4; ++r) {
                    int n = nbase + mt * 16 + hi * 4 + r;
                    qp[(size_t)n * HD_] = __float2bfloat16((acc[mt][jt][r] + bias) * 0.125f);
                }
        } else if (j16 < 1024) {
            const int jj = j16 - 512;
            const int h = jj >> 6, d = (jj & 63) + lo;
            bf16* kp = Kb + ((size_t)(b * NH_ + h) * N_) * HD_ + d;
#pragma unroll
            for (int mt = 0; mt < 4; ++mt)
#pragma unroll
                for (int r = 0; r < 4; ++r) {
                    int n = nbase + mt * 16 + hi * 4 + r;
                    kp[(size_t)n * HD_] = __float2bfloat16(acc[mt][jt][r] + bias);
                }
        } else {
            const int jj = j16 - 1024;
            const int h = jj >> 6, dbase = jj & 63;
            bf16* vp = Vt + ((size_t)(b * NH_ + h) * HD_ + dbase) * N_ + nbase;
#pragma unroll
            for (int mt = 0; mt < 4; ++mt) {
#pragma unroll
                for (int r = 0; r < 4; ++r)
                    Vl[w][hi * 4 + r][lo] = __float2bfloat16(acc[mt][jt][r] + bias);
#pragma unroll
                for (int r = 0; r < 4; ++r)
                    vp[(size_t)(hi * 4 + r) * N_ + mt * 16 + lo] = Vl[w][lo][hi * 4 + r];
            }
        }
    }
}

// ---------------- MFMA flash attention: paired q-tiles + register prefetch ----------------
// R6's proven structure (paired tiles (pi,63-pi), shared K/V loads, 32 keys/iter,
// no-max linear softmax, LDS P-transpose) + manual 2x-unrolled register
// double-buffering: loads for kb+1 stream while kb computes, so the vmcnt wait
// lands after ~600 cy of compute instead of before it.
// blockIdx = blk*64 + bh -> XCD = bh & 7 (per-XCD K/V working set ~3 MB in L2).

__device__ __forceinline__ void attn_chain(
    const bf16x8& q0, const bf16x8& q1,
    const bf16x8* k, const bf16x8* v,
    int qw, int key0, int lo, int hi,
    bf16 (*pl)[40], f32x4* O, float* Lp)
{
    f32x4 S0 = {0.f, 0.f, 0.f, 0.f};
    f32x4 S1 = {0.f, 0.f, 0.f, 0.f};
    S0 = mfma16(q0, k[0], S0);
    S0 = mfma16(q1, k[1], S0);
    S1 = mfma16(q0, k[2], S1);
    S1 = mfma16(q1, k[3], S1);

    if (key0 + 31 > qw) {
#pragma unroll
        for (int r = 0; r < 4; ++r) {
            int q = qw + hi * 4 + r;
            if (key0 + lo > q)      S0[r] = -1e30f;
            if (key0 + 16 + lo > q) S1[r] = -1e30f;
        }
    }

#pragma unroll
    for (int r = 0; r < 4; ++r) {
        float p0 = __expf(S0[r]);
        float p1 = __expf(S1[r]);
        Lp[r] += p0 + p1;
        pl[hi * 4 + r][lo]      = __float2bfloat16(p0);
        pl[hi * 4 + r][16 + lo] = __float2bfloat16(p1);
    }

    bf16x8 pa = *(const bf16x8*)(&pl[lo][hi * 8]);
    O[0] = mfma16(pa, v[0], O[0]);
    O[1] = mfma16(pa, v[1], O[1]);
    O[2] = mfma16(pa, v[2], O[2]);
    O[3] = mfma16(pa, v[3], O[3]);
}

__device__ __forceinline__ void load_kv(const bf16* Kh, const bf16* Vh,
                                        int key0, int lo, int hi,
                                        bf16x8* k, bf16x8* v)
{
    const bf16* kp = Kh + (size_t)(key0 + lo) * HD_ + hi * 8;
    k[0] = *(const bf16x8*)(kp);
    k[1] = *(const bf16x8*)(kp + 32);
    k[2] = *(const bf16x8*)(kp + 16 * HD_);
    k[3] = *(const bf16x8*)(kp + 16 * HD_ + 32);
    const bf16* vp = Vh + (size_t)lo * N_ + key0 + hi * 8;
    v[0] = *(const bf16x8*)(vp);
    v[1] = *(const bf16x8*)(vp + 16 * N_);
    v[2] = *(const bf16x8*)(vp + 32 * N_);
    v[3] = *(const bf16x8*)(vp + 48 * N_);
}

__global__ __launch_bounds__(256) void attn_mfma(const bf16* __restrict__ Qb,
                                                 const bf16* __restrict__ Kb,
                                                 const bf16* __restrict__ Vt,
                                                 bf16* __restrict__ ao) {
    __shared__ __align__(16) bf16 Pl[4][2][16][40];
    const int wv   = threadIdx.x >> 6;
    const int lane = threadIdx.x & 63;
    const int lo   = lane & 15;
    const int hi   = lane >> 4;
    const int bh   = blockIdx.x & 63;            // XCD = bh & 7
    const int pi   = (blockIdx.x >> 6) * 4 + wv; // 0..31
    const int qwA  = pi * 16;
    const int qwB  = (63 - pi) * 16;

    const bf16* Qh = Qb + (size_t)bh * N_ * HD_;
    const bf16* Kh = Kb + (size_t)bh * N_ * HD_;
    const bf16* Vh = Vt + (size_t)bh * HD_ * N_;

    const bf16x8 qA0 = *(const bf16x8*)(Qh + (qwA + lo) * HD_ + hi * 8);
    const bf16x8 qA1 = *(const bf16x8*)(Qh + (qwA + lo) * HD_ + 32 + hi * 8);
    const bf16x8 qB0 = *(const bf16x8*)(Qh + (qwB + lo) * HD_ + hi * 8);
    const bf16x8 qB1 = *(const bf16x8*)(Qh + (qwB + lo) * HD_ + 32 + hi * 8);

    f32x4 OA[4], OB[4];
    float LA[4], LB[4];
#pragma unroll
    for (int r = 0; r < 4; ++r) {
        OA[0][r] = OA[1][r] = OA[2][r] = OA[3][r] = 0.f;
        OB[0][r] = OB[1][r] = OB[2][r] = OB[3][r] = 0.f;
        LA[r] = 0.f; LB[r] = 0.f;
    }

    const int nkbA = (qwA + 47) >> 5;
    const int nkbB = (qwB + 47) >> 5;

    bf16x8 k0f[4], v0f[4], k1f[4], v1f[4];   // ping-pong register buffers
    load_kv(Kh, Vh, 0, lo, hi, k0f, v0f);

    auto process = [&](int kb, const bf16x8* k, const bf16x8* v) {
        const int key0 = kb * 32;
        attn_chain(qB0, qB1, k, v, qwB, key0, lo, hi, Pl[wv][1], OB, LB);
        if (kb < nkbA)
            attn_chain(qA0, qA1, k, v, qwA, key0, lo, hi, Pl[wv][0], OA, LA);
    };

    int kb = 0;
    while (true) {
        if (kb + 1 < nkbB) load_kv(Kh, Vh, (kb + 1) * 32, lo, hi, k1f, v1f);
        process(kb, k0f, v0f);
        if (++kb >= nkbB) break;
        if (kb + 1 < nkbB) load_kv(Kh, Vh, (kb + 1) * 32, lo, hi, k0f, v0f);
        process(kb, k1f, v1f);
        if (++kb >= nkbB) break;
    }

    const int b = bh >> 3, h = bh & 7;
#pragma unroll
    for (int c = 0; c < 2; ++c) {
        const int qw = c ? qwB : qwA;
        f32x4* O = c ? OB : OA;
        float* Lp = c ? LB : LA;
        float rL[4];
#pragma unroll
        for (int r = 0; r < 4; ++r) {
            float Ls = Lp[r];
#pragma unroll
            for (int off = 1; off < 16; off <<= 1)
                Ls += __shfl_xor(Ls, off, 64);
            rL[r] = 1.f / Ls;
        }
#pragma unroll
        for (int t = 0; t < 4; ++t)
#pragma unroll
            for (int r = 0; r < 4; ++r) {
                int q = qw + hi * 4 + r;
                ao[((size_t)b * N_ + q) * C_ + h * HD_ + t * 16 + lo] =
                    __float2bfloat16(O[t][r] * rL[r]);
            }
    }
}

// ---------------- Projection GEMM: 512x8192x512, 64j x 128n tiles, LDS-staged ----------------
__global__ __launch_bounds__(256) void proj_mfma(const bf16* __restrict__ aob,
                                                 const bf16* __restrict__ Wpb,
                                                 const float* __restrict__ bp,
                                                 float* __restrict__ out) {
    __shared__ bf16 As[64 * 32];
    __shared__ bf16 Bs[128 * 32];
    const int tid = threadIdx.x, w = tid >> 6, lane = tid & 63;
    const int lo = lane & 15, hi = lane >> 4;
    const int j0 = blockIdx.x * 64;
    const int n0 = blockIdx.y * 128;
    const int b  = n0 >> 10;

    const int r4 = lane >> 2, c8 = (lane & 3) * 8;
    const bf16* gA = Wpb + (size_t)(j0 + w * 16 + r4) * C_ + c8;
    const bf16* gB = aob + (size_t)(n0 + w * 32 + r4) * C_ + c8;
    bf16* lA = As + (w * 16) * 32;
    bf16* lB = Bs + (w * 32) * 32;

    f32x4 acc[2][4];
#pragma unroll
    for (int mt = 0; mt < 2; ++mt)
#pragma unroll
        for (int jt = 0; jt < 4; ++jt)
            acc[mt][jt] = (f32x4){0.f, 0.f, 0.f, 0.f};

    for (int k0 = 0; k0 < C_; k0 += 32) {
        ld_lds16(gA + k0, lA);
        ld_lds16(gB + k0, lB);
        ld_lds16(gB + (size_t)16 * C_ + k0, lB + 16 * 32);
        __syncthreads();

        bf16x8 af[2], bfr[4];
#pragma unroll
        for (int mt = 0; mt < 2; ++mt)
            af[mt] = *(const bf16x8*)(As + ((w & 1) * 32 + mt * 16 + lo) * 32 + hi * 8);
#pragma unroll
        for (int jt = 0; jt < 4; ++jt)
            bfr[jt] = *(const bf16x8*)(Bs + ((w >> 1) * 64 + jt * 16 + lo) * 32 + hi * 8);
#pragma unroll
        for (int mt = 0; mt < 2; ++mt)
#pragma unroll
            for (int jt = 0; jt < 4; ++jt)
                acc[mt][jt] = mfma16(af[mt], bfr[jt], acc[mt][jt]);
        __syncthreads();
    }

#pragma unroll
    for (int mt = 0; mt < 2; ++mt)
#pragma unroll
        for (int r = 0; r < 4; ++r) {
            const int j = j0 + (w & 1) * 32 + mt * 16 + hi * 4 + r;
            const float bias = bp[j];
            float* op = out + ((size_t)(b * C_ + j)) * N_ + (n0 & 1023) + (w >> 1) * 64 + lo;
#pragma unroll
            for (int jt = 0; jt < 4; ++jt)
                op[jt * 16] = acc[mt][jt][r] + bias;
        }
}

extern "C" void kernel_launch(void* const* d_in, const int* in_sizes, int n_in,
                              void* d_out, int out_size, void* d_ws, size_t ws_size,
                              hipStream_t stream) {
    const float* x  = (const float*)d_in[0];
    const float* Wq = (const float*)d_in[1];
    const float* bq = (const float*)d_in[2];
    const float* Wp = (const float*)d_in[3];
    const float* bp = (const float*)d_in[4];
    float* out = (float*)d_out;

    const size_t headElems = (size_t)B_ * NH_ * N_ * HD_;
    bf16* xb  = (bf16*)d_ws;
    bf16* Wqb = xb + (size_t)B_ * N_ * C_;
    bf16* Wpb = Wqb + (size_t)C3_ * C_;
    bf16* Qb  = Wpb + (size_t)C_ * C_;
    bf16* Kb  = Qb + headElems;
    bf16* Vt  = Kb + headElems;
    bf16* aob = Vt + headElems;

    cvt_w<<<dim3((C3_ * C_ + C_ * C_ + 255) / 256), dim3(256), 0, stream>>>(Wq, Wp, Wqb, Wpb);
    transpose_x<<<dim3(N_ / 32, C_ / 32, B_), dim3(32, 8), 0, stream>>>(x, xb);

    qkv_mfma<<<dim3(C3_ / 128, (B_ * N_) / 128), dim3(256), 0, stream>>>(xb, Wqb, bq, Qb, Kb, Vt);
    attn_mfma<<<dim3(8 * 64), dim3(256), 0, stream>>>(Qb, Kb, Vt, aob);
    proj_mfma<<<dim3(C_ / 64, (B_ * N_) / 128), dim3(256), 0, stream>>>(aob, Wpb, bp, out);
}

// Round 12
// 142.437 us; speedup vs baseline: 1.3531x; 1.1906x over previous
//
#include <hip/hip_runtime.h>
#include <hip/hip_bf16.h>
#include <math.h>

#define B_  8
#define C_  512
#define N_  1024
#define NH_ 8
#define HD_ 64
#define C3_ 1536

typedef __bf16 bf16x8 __attribute__((ext_vector_type(8)));
typedef float  f32x4  __attribute__((ext_vector_type(4)));
typedef __hip_bfloat16 bf16;

__device__ __forceinline__ f32x4 mfma16(const bf16x8& a, const bf16x8& b, const f32x4& c) {
    return __builtin_amdgcn_mfma_f32_16x16x32_bf16(a, b, c, 0, 0, 0);
}

// async global->LDS, 16B per lane. LDS dest = wave-uniform base + lane*16.
__device__ __forceinline__ void ld_lds16(const bf16* g, bf16* l_uniform) {
    __builtin_amdgcn_global_load_lds(
        (const __attribute__((address_space(1))) void*)(uintptr_t)g,
        (__attribute__((address_space(3))) void*)(uintptr_t)l_uniform,
        16, 0, 0);
}

// ---------------- prep ----------------

__global__ __launch_bounds__(256) void cvt_w(const float* __restrict__ Wq,
                                             const float* __restrict__ Wp,
                                             bf16* __restrict__ Wqb,
                                             bf16* __restrict__ Wpb) {
    int i = blockIdx.x * 256 + threadIdx.x;
    if (i < C3_ * C_) Wqb[i] = __float2bfloat16(Wq[i]);
    else {
        int j = i - C3_ * C_;
        if (j < C_ * C_) Wpb[j] = __float2bfloat16(Wp[j]);
    }
}

// x (B, C, N) f32  ->  xb (B, N, C) bf16
__global__ __launch_bounds__(256) void transpose_x(const float* __restrict__ x,
                                                   bf16* __restrict__ xb) {
    __shared__ float T[32][33];
    const int n0 = blockIdx.x * 32, c0 = blockIdx.y * 32, b = blockIdx.z;
    const int tx = threadIdx.x, ty = threadIdx.y;
    const float* xp = x + ((size_t)b * C_ + c0) * N_ + n0;
#pragma unroll
    for (int l = 0; l < 4; ++l)
        T[ty + 8 * l][tx] = xp[(ty + 8 * l) * N_ + tx];
    __syncthreads();
    bf16* xo = xb + ((size_t)b * N_ + n0) * C_ + c0;
#pragma unroll
    for (int l = 0; l < 4; ++l)
        xo[(ty + 8 * l) * C_ + tx] = __float2bfloat16(T[tx][ty + 8 * l]);
}

// ---------------- QKV GEMM: 8192x1536x512, 128x128 tiles, LDS-staged ----------------
__global__ __launch_bounds__(256) void qkv_mfma(const bf16* __restrict__ xb,
                                                const bf16* __restrict__ Wqb,
                                                const float* __restrict__ bq,
                                                bf16* __restrict__ Qb,
                                                bf16* __restrict__ Kb,
                                                bf16* __restrict__ Vt) {
    __shared__ bf16 As[128 * 32];
    __shared__ bf16 Bs[128 * 32];
    __shared__ bf16 Vl[4][16][20];
    const int tid = threadIdx.x, w = tid >> 6, lane = tid & 63;
    const int lo = lane & 15, hi = lane >> 4;
    const int j0 = blockIdx.x * 128;
    const int m0 = blockIdx.y * 128;
    const int b  = m0 >> 10;

    const int srow = w * 32 + (lane >> 2);
    const int scol = (lane & 3) * 8;
    const bf16* gA = xb  + (size_t)(m0 + srow) * C_ + scol;
    const bf16* gB = Wqb + (size_t)(j0 + srow) * C_ + scol;
    bf16* lA = As + (w * 32) * 32;
    bf16* lB = Bs + (w * 32) * 32;

    f32x4 acc[4][4];
#pragma unroll
    for (int mt = 0; mt < 4; ++mt)
#pragma unroll
        for (int jt = 0; jt < 4; ++jt)
            acc[mt][jt] = (f32x4){0.f, 0.f, 0.f, 0.f};

    for (int k0 = 0; k0 < C_; k0 += 32) {
        ld_lds16(gA + k0, lA);
        ld_lds16(gA + (size_t)16 * C_ + k0, lA + 16 * 32);
        ld_lds16(gB + k0, lB);
        ld_lds16(gB + (size_t)16 * C_ + k0, lB + 16 * 32);
        __syncthreads();

        bf16x8 af[4], bfr[4];
#pragma unroll
        for (int mt = 0; mt < 4; ++mt)
            af[mt] = *(const bf16x8*)(As + ((w & 1) * 64 + mt * 16 + lo) * 32 + hi * 8);
#pragma unroll
        for (int jt = 0; jt < 4; ++jt)
            bfr[jt] = *(const bf16x8*)(Bs + ((w >> 1) * 64 + jt * 16 + lo) * 32 + hi * 8);
#pragma unroll
        for (int mt = 0; mt < 4; ++mt)
#pragma unroll
            for (int jt = 0; jt < 4; ++jt)
                acc[mt][jt] = mfma16(af[mt], bfr[jt], acc[mt][jt]);
        __syncthreads();
    }

    const int jb = (w >> 1) * 64;
    const int nbase = (m0 & 1023) + (w & 1) * 64;
#pragma unroll
    for (int jt = 0; jt < 4; ++jt) {
        const int j16 = j0 + jb + jt * 16;
        const float bias = bq[j16 + lo];
        if (j16 < 512) {
            const int h = j16 >> 6, d = (j16 & 63) + lo;
            bf16* qp = Qb + ((size_t)(b * NH_ + h) * N_) * HD_ + d;
#pragma unroll
            for (int mt = 0; mt < 4; ++mt)
#pragma unroll
                for (int r = 0; r < 4; ++r) {
                    int n = nbase + mt * 16 + hi * 4 + r;
                    qp[(size_t)n * HD_] = __float2bfloat16((acc[mt][jt][r] + bias) * 0.125f);
                }
        } else if (j16 < 1024) {
            const int jj = j16 - 512;
            const int h = jj >> 6, d = (jj & 63) + lo;
            bf16* kp = Kb + ((size_t)(b * NH_ + h) * N_) * HD_ + d;
#pragma unroll
            for (int mt = 0; mt < 4; ++mt)
#pragma unroll
                for (int r = 0; r < 4; ++r) {
                    int n = nbase + mt * 16 + hi * 4 + r;
                    kp[(size_t)n * HD_] = __float2bfloat16(acc[mt][jt][r] + bias);
                }
        } else {
            const int jj = j16 - 1024;
            const int h = jj >> 6, dbase = jj & 63;
            bf16* vp = Vt + ((size_t)(b * NH_ + h) * HD_ + dbase) * N_ + nbase;
#pragma unroll
            for (int mt = 0; mt < 4; ++mt) {
#pragma unroll
                for (int r = 0; r < 4; ++r)
                    Vl[w][hi * 4 + r][lo] = __float2bfloat16(acc[mt][jt][r] + bias);
#pragma unroll
                for (int r = 0; r < 4; ++r)
                    vp[(size_t)(hi * 4 + r) * N_ + mt * 16 + lo] = Vl[w][lo][hi * 4 + r];
            }
        }
    }
}

// ---------------- MFMA flash attention: block-shared LDS K/V staging ----------------
// All 4 waves of a block consume the same (b,h) key stream -> stage K/V tiles
// (64 keys) into LDS once per block via global_load_lds (m97 2-barrier loop),
// cutting L1/L2 request traffic 4x. Compute body = R8's 64-key paired-chain
// version (verified), fragments read from LDS half-tiles (qkv-staging bank
// layout). Uniform loop bound = wv0's B-chain; short waves predicate compute.
// blockIdx = blk*64 + bh -> XCD = bh & 7 (per-XCD K/V working set ~3 MB in L2).

__global__ __launch_bounds__(256) void attn_mfma(const bf16* __restrict__ Qb,
                                                 const bf16* __restrict__ Kb,
                                                 const bf16* __restrict__ Vt,
                                                 bf16* __restrict__ ao) {
    __shared__ bf16 Ks0[64 * 32], Ks1[64 * 32];   // [key][d 0-31], [key][d 32-63]
    __shared__ bf16 Vs0[64 * 32], Vs1[64 * 32];   // [d][key 0-31], [d][key 32-63]
    __shared__ __align__(16) bf16 Pl[4][2][2][16][40];

    const int tid  = threadIdx.x;
    const int wv   = tid >> 6;
    const int lane = tid & 63;
    const int lo   = lane & 15;
    const int hi   = lane >> 4;
    const int bh   = blockIdx.x & 63;            // XCD = bh & 7
    const int blk  = blockIdx.x >> 6;            // 0..7
    const int pi   = blk * 4 + wv;               // 0..31
    const int qwA  = pi * 16;
    const int qwB  = (63 - pi) * 16;

    const bf16* Qh = Qb + (size_t)bh * N_ * HD_;
    const bf16* Kh = Kb + (size_t)bh * N_ * HD_;
    const bf16* Vh = Vt + (size_t)bh * HD_ * N_;

    const bf16x8 qA0 = *(const bf16x8*)(Qh + (qwA + lo) * HD_ + hi * 8);
    const bf16x8 qA1 = *(const bf16x8*)(Qh + (qwA + lo) * HD_ + 32 + hi * 8);
    const bf16x8 qB0 = *(const bf16x8*)(Qh + (qwB + lo) * HD_ + hi * 8);
    const bf16x8 qB1 = *(const bf16x8*)(Qh + (qwB + lo) * HD_ + 32 + hi * 8);

    // staging addresses: 256 threads x 16B = one 64-row x 32-col half-tile
    const int srow = tid >> 2;                   // 0..63
    const int scol = (tid & 3) * 8;              // 0,8,16,24
    const bf16* gK = Kh + (size_t)srow * HD_ + scol;
    const bf16* gV = Vh + (size_t)srow * N_ + scol;
    bf16* lK0 = Ks0 + wv * 512;                  // wave-uniform LDS bases
    bf16* lK1 = Ks1 + wv * 512;
    bf16* lV0 = Vs0 + wv * 512;
    bf16* lV1 = Vs1 + wv * 512;

    f32x4 OA[4], OB[4];
    float LA[4], LB[4];
#pragma unroll
    for (int r = 0; r < 4; ++r) {
        OA[0][r] = OA[1][r] = OA[2][r] = OA[3][r] = 0.f;
        OB[0][r] = OB[1][r] = OB[2][r] = OB[3][r] = 0.f;
        LA[r] = 0.f; LB[r] = 0.f;
    }

    const int nkbA   = (qwA + 79) >> 6;          // 64-key blocks for chain A
    const int nkbB   = (qwB + 79) >> 6;
    const int nkbBlk = ((63 - blk * 4) * 16 + 79) >> 6;   // wv0's B-chain (longest)

    for (int kb = 0; kb < nkbBlk; ++kb) {
        const int key0 = kb * 64;

        ld_lds16(gK + (size_t)key0 * HD_,      lK0);
        ld_lds16(gK + (size_t)key0 * HD_ + 32, lK1);
        ld_lds16(gV + key0,                    lV0);
        ld_lds16(gV + key0 + 32,               lV1);
        __syncthreads();                         // staging drained, tiles valid

        if (kb < nkbB) {
            const bool doA = (kb < nkbA);

            // fragments from LDS (qkv-proven bank layout)
            bf16x8 kf[4][2], vf[4][2];
#pragma unroll
            for (int t = 0; t < 4; ++t) {
                kf[t][0] = *(const bf16x8*)(Ks0 + (t * 16 + lo) * 32 + hi * 8);
                kf[t][1] = *(const bf16x8*)(Ks1 + (t * 16 + lo) * 32 + hi * 8);
                vf[t][0] = *(const bf16x8*)(Vs0 + (t * 16 + lo) * 32 + hi * 8);
                vf[t][1] = *(const bf16x8*)(Vs1 + (t * 16 + lo) * 32 + hi * 8);
            }

            f32x4 SB[4], SA[4];
#pragma unroll
            for (int t = 0; t < 4; ++t) {
                SB[t] = (f32x4){0.f, 0.f, 0.f, 0.f};
                SB[t] = mfma16(qB0, kf[t][0], SB[t]);
                SB[t] = mfma16(qB1, kf[t][1], SB[t]);
            }
            if (doA) {
#pragma unroll
                for (int t = 0; t < 4; ++t) {
                    SA[t] = (f32x4){0.f, 0.f, 0.f, 0.f};
                    SA[t] = mfma16(qA0, kf[t][0], SA[t]);
                    SA[t] = mfma16(qA1, kf[t][1], SA[t]);
                }
            }

            if (key0 + 63 > qwB) {
#pragma unroll
                for (int t = 0; t < 4; ++t)
#pragma unroll
                    for (int r = 0; r < 4; ++r)
                        if (key0 + t * 16 + lo > qwB + hi * 4 + r) SB[t][r] = -1e30f;
            }
            if (doA && key0 + 63 > qwA) {
#pragma unroll
                for (int t = 0; t < 4; ++t)
#pragma unroll
                    for (int r = 0; r < 4; ++r)
                        if (key0 + t * 16 + lo > qwA + hi * 4 + r) SA[t][r] = -1e30f;
            }

#pragma unroll
            for (int t = 0; t < 4; ++t)
#pragma unroll
                for (int r = 0; r < 4; ++r) {
                    float p = __expf(SB[t][r]);
                    LB[r] += p;
                    Pl[wv][1][t >> 1][hi * 4 + r][(t & 1) * 16 + lo] = __float2bfloat16(p);
                }
            if (doA) {
#pragma unroll
                for (int t = 0; t < 4; ++t)
#pragma unroll
                    for (int r = 0; r < 4; ++r) {
                        float p = __expf(SA[t][r]);
                        LA[r] += p;
                        Pl[wv][0][t >> 1][hi * 4 + r][(t & 1) * 16 + lo] = __float2bfloat16(p);
                    }
            }

            bf16x8 paB0 = *(const bf16x8*)(&Pl[wv][1][0][lo][hi * 8]);
            bf16x8 paB1 = *(const bf16x8*)(&Pl[wv][1][1][lo][hi * 8]);
#pragma unroll
            for (int t = 0; t < 4; ++t) {
                OB[t] = mfma16(paB0, vf[t][0], OB[t]);
                OB[t] = mfma16(paB1, vf[t][1], OB[t]);
            }
            if (doA) {
                bf16x8 paA0 = *(const bf16x8*)(&Pl[wv][0][0][lo][hi * 8]);
                bf16x8 paA1 = *(const bf16x8*)(&Pl[wv][0][1][lo][hi * 8]);
#pragma unroll
                for (int t = 0; t < 4; ++t) {
                    OA[t] = mfma16(paA0, vf[t][0], OA[t]);
                    OA[t] = mfma16(paA1, vf[t][1], OA[t]);
                }
            }
        }
        __syncthreads();                         // all reads done before restage
    }

    const int b = bh >> 3, h = bh & 7;
#pragma unroll
    for (int c = 0; c < 2; ++c) {
        const int qw = c ? qwB : qwA;
        f32x4* O = c ? OB : OA;
        float* Lp = c ? LB : LA;
        float rL[4];
#pragma unroll
        for (int r = 0; r < 4; ++r) {
            float Ls = Lp[r];
#pragma unroll
            for (int off = 1; off < 16; off <<= 1)
                Ls += __shfl_xor(Ls, off, 64);
            rL[r] = 1.f / Ls;
        }
#pragma unroll
        for (int t = 0; t < 4; ++t)
#pragma unroll
            for (int r = 0; r < 4; ++r) {
                int q = qw + hi * 4 + r;
                ao[((size_t)b * N_ + q) * C_ + h * HD_ + t * 16 + lo] =
                    __float2bfloat16(O[t][r] * rL[r]);
            }
    }
}

// ---------------- Projection GEMM: 512x8192x512, 64j x 128n tiles, LDS-staged ----------------
__global__ __launch_bounds__(256) void proj_mfma(const bf16* __restrict__ aob,
                                                 const bf16* __restrict__ Wpb,
                                                 const float* __restrict__ bp,
                                                 float* __restrict__ out) {
    __shared__ bf16 As[64 * 32];
    __shared__ bf16 Bs[128 * 32];
    const int tid = threadIdx.x, w = tid >> 6, lane = tid & 63;
    const int lo = lane & 15, hi = lane >> 4;
    const int j0 = blockIdx.x * 64;
    const int n0 = blockIdx.y * 128;
    const int b  = n0 >> 10;

    const int r4 = lane >> 2, c8 = (lane & 3) * 8;
    const bf16* gA = Wpb + (size_t)(j0 + w * 16 + r4) * C_ + c8;
    const bf16* gB = aob + (size_t)(n0 + w * 32 + r4) * C_ + c8;
    bf16* lA = As + (w * 16) * 32;
    bf16* lB = Bs + (w * 32) * 32;

    f32x4 acc[2][4];
#pragma unroll
    for (int mt = 0; mt < 2; ++mt)
#pragma unroll
        for (int jt = 0; jt < 4; ++jt)
            acc[mt][jt] = (f32x4){0.f, 0.f, 0.f, 0.f};

    for (int k0 = 0; k0 < C_; k0 += 32) {
        ld_lds16(gA + k0, lA);
        ld_lds16(gB + k0, lB);
        ld_lds16(gB + (size_t)16 * C_ + k0, lB + 16 * 32);
        __syncthreads();

        bf16x8 af[2], bfr[4];
#pragma unroll
        for (int mt = 0; mt < 2; ++mt)
            af[mt] = *(const bf16x8*)(As + ((w & 1) * 32 + mt * 16 + lo) * 32 + hi * 8);
#pragma unroll
        for (int jt = 0; jt < 4; ++jt)
            bfr[jt] = *(const bf16x8*)(Bs + ((w >> 1) * 64 + jt * 16 + lo) * 32 + hi * 8);
#pragma unroll
        for (int mt = 0; mt < 2; ++mt)
#pragma unroll
            for (int jt = 0; jt < 4; ++jt)
                acc[mt][jt] = mfma16(af[mt], bfr[jt], acc[mt][jt]);
        __syncthreads();
    }

#pragma unroll
    for (int mt = 0; mt < 2; ++mt)
#pragma unroll
        for (int r = 0; r < 4; ++r) {
            const int j = j0 + (w & 1) * 32 + mt * 16 + hi * 4 + r;
            const float bias = bp[j];
            float* op = out + ((size_t)(b * C_ + j)) * N_ + (n0 & 1023) + (w >> 1) * 64 + lo;
#pragma unroll
            for (int jt = 0; jt < 4; ++jt)
                op[jt * 16] = acc[mt][jt][r] + bias;
        }
}

extern "C" void kernel_launch(void* const* d_in, const int* in_sizes, int n_in,
                              void* d_out, int out_size, void* d_ws, size_t ws_size,
                              hipStream_t stream) {
    const float* x  = (const float*)d_in[0];
    const float* Wq = (const float*)d_in[1];
    const float* bq = (const float*)d_in[2];
    const float* Wp = (const float*)d_in[3];
    const float* bp = (const float*)d_in[4];
    float* out = (float*)d_out;

    const size_t headElems = (size_t)B_ * NH_ * N_ * HD_;
    bf16* xb  = (bf16*)d_ws;
    bf16* Wqb = xb + (size_t)B_ * N_ * C_;
    bf16* Wpb = Wqb + (size_t)C3_ * C_;
    bf16* Qb  = Wpb + (size_t)C_ * C_;
    bf16* Kb  = Qb + headElems;
    bf16* Vt  = Kb + headElems;
    bf16* aob = Vt + headElems;

    cvt_w<<<dim3((C3_ * C_ + C_ * C_ + 255) / 256), dim3(256), 0, stream>>>(Wq, Wp, Wqb, Wpb);
    transpose_x<<<dim3(N_ / 32, C_ / 32, B_), dim3(32, 8), 0, stream>>>(x, xb);

    qkv_mfma<<<dim3(C3_ / 128, (B_ * N_) / 128), dim3(256), 0, stream>>>(xb, Wqb, bq, Qb, Kb, Vt);
    attn_mfma<<<dim3(8 * 64), dim3(256), 0, stream>>>(Qb, Kb, Vt, aob);
    proj_mfma<<<dim3(C_ / 64, (B_ * N_) / 128), dim3(256), 0, stream>>>(aob, Wpb, bp, out);
}

// Round 13
// 139.374 us; speedup vs baseline: 1.3829x; 1.0220x over previous
//
#include <hip/hip_runtime.h>
#include <hip/hip_bf16.h>
#include <math.h>

#define B_  8
#define C_  512
#define N_  1024
#define NH_ 8
#define HD_ 64
#define C3_ 1536

typedef __bf16 bf16x8  __attribute__((ext_vector_type(8)));
typedef __bf16 bf16x4v __attribute__((ext_vector_type(4)));
typedef float  f32x4   __attribute__((ext_vector_type(4)));
typedef __hip_bfloat16 bf16;

__device__ __forceinline__ f32x4 mfma16(const bf16x8& a, const bf16x8& b, const f32x4& c) {
    return __builtin_amdgcn_mfma_f32_16x16x32_bf16(a, b, c, 0, 0, 0);
}

// async global->LDS, 16B per lane. LDS dest = wave-uniform base + lane*16.
__device__ __forceinline__ void ld_lds16(const bf16* g, bf16* l_uniform) {
    __builtin_amdgcn_global_load_lds(
        (const __attribute__((address_space(1))) void*)(uintptr_t)g,
        (__attribute__((address_space(3))) void*)(uintptr_t)l_uniform,
        16, 0, 0);
}

// ---------------- prep: x transpose + weight conversion, one launch ----------------
// blocks [0,4096): x (B,C,N) f32 -> xb (B,N,C) bf16 (32x32 LDS tiles)
// blocks [4096,5120): Wq/Wp f32 -> bf16, 4 elems/thread vectorized
__global__ __launch_bounds__(256) void prep(const float* __restrict__ x,
                                            const float* __restrict__ Wq,
                                            const float* __restrict__ Wp,
                                            bf16* __restrict__ xb,
                                            bf16* __restrict__ Wqb,
                                            bf16* __restrict__ Wpb) {
    const int tid = threadIdx.x;
    if (blockIdx.x < 4096) {
        __shared__ float T[32][33];
        int t = blockIdx.x;
        const int n0 = (t & 31) * 32; t >>= 5;
        const int c0 = (t & 15) * 32; t >>= 4;
        const int b  = t;
        const int tx = tid & 31, ty = tid >> 5;
        const float* xp = x + ((size_t)b * C_ + c0) * N_ + n0;
#pragma unroll
        for (int l = 0; l < 4; ++l)
            T[ty + 8 * l][tx] = xp[(ty + 8 * l) * N_ + tx];
        __syncthreads();
        bf16* xo = xb + ((size_t)b * N_ + n0) * C_ + c0;
#pragma unroll
        for (int l = 0; l < 4; ++l)
            xo[(ty + 8 * l) * C_ + tx] = __float2bfloat16(T[tx][ty + 8 * l]);
    } else {
        const int base = (blockIdx.x - 4096) * 1024 + tid * 4;   // 4 elems/thread
        const float* src;
        bf16* dst;
        int off;
        if (base < C3_ * C_) { src = Wq; dst = Wqb; off = base; }
        else                 { src = Wp; dst = Wpb; off = base - C3_ * C_; }
        f32x4 w = *(const f32x4*)(src + off);
        bf16x4v o;
#pragma unroll
        for (int i = 0; i < 4; ++i) o[i] = (__bf16)w[i];
        *(bf16x4v*)(dst + off) = o;
    }
}

// ---------------- QKV GEMM: 8192x1536x512, 128x128 tiles, LDS-staged ----------------
__global__ __launch_bounds__(256) void qkv_mfma(const bf16* __restrict__ xb,
                                                const bf16* __restrict__ Wqb,
                                                const float* __restrict__ bq,
                                                bf16* __restrict__ Qb,
                                                bf16* __restrict__ Kb,
                                                bf16* __restrict__ Vt) {
    __shared__ bf16 As[128 * 32];
    __shared__ bf16 Bs[128 * 32];
    __shared__ bf16 Vl[4][16][20];
    const int tid = threadIdx.x, w = tid >> 6, lane = tid & 63;
    const int lo = lane & 15, hi = lane >> 4;
    const int j0 = blockIdx.x * 128;
    const int m0 = blockIdx.y * 128;
    const int b  = m0 >> 10;

    const int srow = w * 32 + (lane >> 2);
    const int scol = (lane & 3) * 8;
    const bf16* gA = xb  + (size_t)(m0 + srow) * C_ + scol;
    const bf16* gB = Wqb + (size_t)(j0 + srow) * C_ + scol;
    bf16* lA = As + (w * 32) * 32;
    bf16* lB = Bs + (w * 32) * 32;

    f32x4 acc[4][4];
#pragma unroll
    for (int mt = 0; mt < 4; ++mt)
#pragma unroll
        for (int jt = 0; jt < 4; ++jt)
            acc[mt][jt] = (f32x4){0.f, 0.f, 0.f, 0.f};

    for (int k0 = 0; k0 < C_; k0 += 32) {
        ld_lds16(gA + k0, lA);
        ld_lds16(gA + (size_t)16 * C_ + k0, lA + 16 * 32);
        ld_lds16(gB + k0, lB);
        ld_lds16(gB + (size_t)16 * C_ + k0, lB + 16 * 32);
        __syncthreads();

        bf16x8 af[4], bfr[4];
#pragma unroll
        for (int mt = 0; mt < 4; ++mt)
            af[mt] = *(const bf16x8*)(As + ((w & 1) * 64 + mt * 16 + lo) * 32 + hi * 8);
#pragma unroll
        for (int jt = 0; jt < 4; ++jt)
            bfr[jt] = *(const bf16x8*)(Bs + ((w >> 1) * 64 + jt * 16 + lo) * 32 + hi * 8);
#pragma unroll
        for (int mt = 0; mt < 4; ++mt)
#pragma unroll
            for (int jt = 0; jt < 4; ++jt)
                acc[mt][jt] = mfma16(af[mt], bfr[jt], acc[mt][jt]);
        __syncthreads();
    }

    const int jb = (w >> 1) * 64;
    const int nbase = (m0 & 1023) + (w & 1) * 64;
#pragma unroll
    for (int jt = 0; jt < 4; ++jt) {
        const int j16 = j0 + jb + jt * 16;
        const float bias = bq[j16 + lo];
        if (j16 < 512) {
            const int h = j16 >> 6, d = (j16 & 63) + lo;
            bf16* qp = Qb + ((size_t)(b * NH_ + h) * N_) * HD_ + d;
#pragma unroll
            for (int mt = 0; mt < 4; ++mt)
#pragma unroll
                for (int r = 0; r < 4; ++r) {
                    int n = nbase + mt * 16 + hi * 4 + r;
                    qp[(size_t)n * HD_] = __float2bfloat16((acc[mt][jt][r] + bias) * 0.125f);
                }
        } else if (j16 < 1024) {
            const int jj = j16 - 512;
            const int h = jj >> 6, d = (jj & 63) + lo;
            bf16* kp = Kb + ((size_t)(b * NH_ + h) * N_) * HD_ + d;
#pragma unroll
            for (int mt = 0; mt < 4; ++mt)
#pragma unroll
                for (int r = 0; r < 4; ++r) {
                    int n = nbase + mt * 16 + hi * 4 + r;
                    kp[(size_t)n * HD_] = __float2bfloat16(acc[mt][jt][r] + bias);
                }
        } else {
            const int jj = j16 - 1024;
            const int h = jj >> 6, dbase = jj & 63;
            bf16* vp = Vt + ((size_t)(b * NH_ + h) * HD_ + dbase) * N_ + nbase;
#pragma unroll
            for (int mt = 0; mt < 4; ++mt) {
#pragma unroll
                for (int r = 0; r < 4; ++r)
                    Vl[w][hi * 4 + r][lo] = __float2bfloat16(acc[mt][jt][r] + bias);
#pragma unroll
                for (int r = 0; r < 4; ++r)
                    vp[(size_t)(hi * 4 + r) * N_ + mt * 16 + lo] = Vl[w][lo][hi * 4 + r];
            }
        }
    }
}

// ---------------- MFMA flash attention: block-shared LDS K/V, double-buffered ----------------
// R12's structure (4 waves share staged K/V tiles, paired q-tiles, no-max softmax)
// + ping-pong staging: tiles for kb+1 are issued right AFTER the barrier and
// stream in while kb computes; the implicit vmcnt(0) before the NEXT barrier
// lands after ~700 cy of compute instead of immediately after issue.
// One barrier per iteration. LDS 42 KB (grid gives 2 blocks/CU; cap is LDS 80 KB).

__global__ __launch_bounds__(256) void attn_mfma(const bf16* __restrict__ Qb,
                                                 const bf16* __restrict__ Kb,
                                                 const bf16* __restrict__ Vt,
                                                 bf16* __restrict__ ao) {
    __shared__ bf16 Ks0[2][64 * 32], Ks1[2][64 * 32];   // [buf][key][d-half]
    __shared__ bf16 Vs0[2][64 * 32], Vs1[2][64 * 32];   // [buf][d][key-half]
    __shared__ __align__(16) bf16 Pl[4][2][2][16][40];

    const int tid  = threadIdx.x;
    const int wv   = tid >> 6;
    const int lane = tid & 63;
    const int lo   = lane & 15;
    const int hi   = lane >> 4;
    const int bh   = blockIdx.x & 63;            // XCD = bh & 7
    const int blk  = blockIdx.x >> 6;            // 0..7
    const int pi   = blk * 4 + wv;               // 0..31
    const int qwA  = pi * 16;
    const int qwB  = (63 - pi) * 16;

    const bf16* Qh = Qb + (size_t)bh * N_ * HD_;
    const bf16* Kh = Kb + (size_t)bh * N_ * HD_;
    const bf16* Vh = Vt + (size_t)bh * HD_ * N_;

    const bf16x8 qA0 = *(const bf16x8*)(Qh + (qwA + lo) * HD_ + hi * 8);
    const bf16x8 qA1 = *(const bf16x8*)(Qh + (qwA + lo) * HD_ + 32 + hi * 8);
    const bf16x8 qB0 = *(const bf16x8*)(Qh + (qwB + lo) * HD_ + hi * 8);
    const bf16x8 qB1 = *(const bf16x8*)(Qh + (qwB + lo) * HD_ + 32 + hi * 8);

    // staging: 256 threads x 16B per call = one 64x32 half-tile
    const int srow = tid >> 2;
    const int scol = (tid & 3) * 8;
    const bf16* gK = Kh + (size_t)srow * HD_ + scol;
    const bf16* gV = Vh + (size_t)srow * N_ + scol;
    const int lofs = wv * 512;                   // wave-uniform LDS offset

    f32x4 OA[4], OB[4];
    float LA[4], LB[4];
#pragma unroll
    for (int r = 0; r < 4; ++r) {
        OA[0][r] = OA[1][r] = OA[2][r] = OA[3][r] = 0.f;
        OB[0][r] = OB[1][r] = OB[2][r] = OB[3][r] = 0.f;
        LA[r] = 0.f; LB[r] = 0.f;
    }

    const int nkbA   = (qwA + 79) >> 6;
    const int nkbB   = (qwB + 79) >> 6;
    const int nkbBlk = ((63 - blk * 4) * 16 + 79) >> 6;

    // prologue: stage kb=0 into buf 0
    {
        ld_lds16(gK,      Ks0[0] + lofs);
        ld_lds16(gK + 32, Ks1[0] + lofs);
        ld_lds16(gV,      Vs0[0] + lofs);
        ld_lds16(gV + 32, Vs1[0] + lofs);
    }

    for (int kb = 0; kb < nkbBlk; ++kb) {
        const int key0 = kb * 64;
        const int cur  = kb & 1;

        __syncthreads();                         // drains cur's staging (covered by prev compute)

        if (kb + 1 < nkbBlk) {                   // prefetch kb+1 into the other buffer
            const size_t nk = (size_t)(key0 + 64);
            ld_lds16(gK + nk * HD_,      Ks0[cur ^ 1] + lofs);
            ld_lds16(gK + nk * HD_ + 32, Ks1[cur ^ 1] + lofs);
            ld_lds16(gV + nk,            Vs0[cur ^ 1] + lofs);
            ld_lds16(gV + nk + 32,       Vs1[cur ^ 1] + lofs);
        }

        if (kb < nkbB) {
            const bool doA = (kb < nkbA);

            bf16x8 kf[4][2], vf[4][2];
#pragma unroll
            for (int t = 0; t < 4; ++t) {
                kf[t][0] = *(const bf16x8*)(Ks0[cur] + (t * 16 + lo) * 32 + hi * 8);
                kf[t][1] = *(const bf16x8*)(Ks1[cur] + (t * 16 + lo) * 32 + hi * 8);
                vf[t][0] = *(const bf16x8*)(Vs0[cur] + (t * 16 + lo) * 32 + hi * 8);
                vf[t][1] = *(const bf16x8*)(Vs1[cur] + (t * 16 + lo) * 32 + hi * 8);
            }

            f32x4 SB[4], SA[4];
#pragma unroll
            for (int t = 0; t < 4; ++t) {
                SB[t] = (f32x4){0.f, 0.f, 0.f, 0.f};
                SB[t] = mfma16(qB0, kf[t][0], SB[t]);
                SB[t] = mfma16(qB1, kf[t][1], SB[t]);
            }
            if (doA) {
#pragma unroll
                for (int t = 0; t < 4; ++t) {
                    SA[t] = (f32x4){0.f, 0.f, 0.f, 0.f};
                    SA[t] = mfma16(qA0, kf[t][0], SA[t]);
                    SA[t] = mfma16(qA1, kf[t][1], SA[t]);
                }
            }

            if (key0 + 63 > qwB) {
#pragma unroll
                for (int t = 0; t < 4; ++t)
#pragma unroll
                    for (int r = 0; r < 4; ++r)
                        if (key0 + t * 16 + lo > qwB + hi * 4 + r) SB[t][r] = -1e30f;
            }
            if (doA && key0 + 63 > qwA) {
#pragma unroll
                for (int t = 0; t < 4; ++t)
#pragma unroll
                    for (int r = 0; r < 4; ++r)
                        if (key0 + t * 16 + lo > qwA + hi * 4 + r) SA[t][r] = -1e30f;
            }

#pragma unroll
            for (int t = 0; t < 4; ++t)
#pragma unroll
                for (int r = 0; r < 4; ++r) {
                    float p = __expf(SB[t][r]);
                    LB[r] += p;
                    Pl[wv][1][t >> 1][hi * 4 + r][(t & 1) * 16 + lo] = __float2bfloat16(p);
                }
            if (doA) {
#pragma unroll
                for (int t = 0; t < 4; ++t)
#pragma unroll
                    for (int r = 0; r < 4; ++r) {
                        float p = __expf(SA[t][r]);
                        LA[r] += p;
                        Pl[wv][0][t >> 1][hi * 4 + r][(t & 1) * 16 + lo] = __float2bfloat16(p);
                    }
            }

            bf16x8 paB0 = *(const bf16x8*)(&Pl[wv][1][0][lo][hi * 8]);
            bf16x8 paB1 = *(const bf16x8*)(&Pl[wv][1][1][lo][hi * 8]);
#pragma unroll
            for (int t = 0; t < 4; ++t) {
                OB[t] = mfma16(paB0, vf[t][0], OB[t]);
                OB[t] = mfma16(paB1, vf[t][1], OB[t]);
            }
            if (doA) {
                bf16x8 paA0 = *(const bf16x8*)(&Pl[wv][0][0][lo][hi * 8]);
                bf16x8 paA1 = *(const bf16x8*)(&Pl[wv][0][1][lo][hi * 8]);
#pragma unroll
                for (int t = 0; t < 4; ++t) {
                    OA[t] = mfma16(paA0, vf[t][0], OA[t]);
                    OA[t] = mfma16(paA1, vf[t][1], OA[t]);
                }
            }
        }
    }

    const int b = bh >> 3, h = bh & 7;
#pragma unroll
    for (int c = 0; c < 2; ++c) {
        const int qw = c ? qwB : qwA;
        f32x4* O = c ? OB : OA;
        float* Lp = c ? LB : LA;
        float rL[4];
#pragma unroll
        for (int r = 0; r < 4; ++r) {
            float Ls = Lp[r];
#pragma unroll
            for (int off = 1; off < 16; off <<= 1)
                Ls += __shfl_xor(Ls, off, 64);
            rL[r] = 1.f / Ls;
        }
#pragma unroll
        for (int t = 0; t < 4; ++t)
#pragma unroll
            for (int r = 0; r < 4; ++r) {
                int q = qw + hi * 4 + r;
                ao[((size_t)b * N_ + q) * C_ + h * HD_ + t * 16 + lo] =
                    __float2bfloat16(O[t][r] * rL[r]);
            }
    }
}

// ---------------- Projection GEMM: 512x8192x512, 64j x 128n tiles, LDS-staged ----------------
__global__ __launch_bounds__(256) void proj_mfma(const bf16* __restrict__ aob,
                                                 const bf16* __restrict__ Wpb,
                                                 const float* __restrict__ bp,
                                                 float* __restrict__ out) {
    __shared__ bf16 As[64 * 32];
    __shared__ bf16 Bs[128 * 32];
    const int tid = threadIdx.x, w = tid >> 6, lane = tid & 63;
    const int lo = lane & 15, hi = lane >> 4;
    const int j0 = blockIdx.x * 64;
    const int n0 = blockIdx.y * 128;
    const int b  = n0 >> 10;

    const int r4 = lane >> 2, c8 = (lane & 3) * 8;
    const bf16* gA = Wpb + (size_t)(j0 + w * 16 + r4) * C_ + c8;
    const bf16* gB = aob + (size_t)(n0 + w * 32 + r4) * C_ + c8;
    bf16* lA = As + (w * 16) * 32;
    bf16* lB = Bs + (w * 32) * 32;

    f32x4 acc[2][4];
#pragma unroll
    for (int mt = 0; mt < 2; ++mt)
#pragma unroll
        for (int jt = 0; jt < 4; ++jt)
            acc[mt][jt] = (f32x4){0.f, 0.f, 0.f, 0.f};

    for (int k0 = 0; k0 < C_; k0 += 32) {
        ld_lds16(gA + k0, lA);
        ld_lds16(gB + k0, lB);
        ld_lds16(gB + (size_t)16 * C_ + k0, lB + 16 * 32);
        __syncthreads();

        bf16x8 af[2], bfr[4];
#pragma unroll
        for (int mt = 0; mt < 2; ++mt)
            af[mt] = *(const bf16x8*)(As + ((w & 1) * 32 + mt * 16 + lo) * 32 + hi * 8);
#pragma unroll
        for (int jt = 0; jt < 4; ++jt)
            bfr[jt] = *(const bf16x8*)(Bs + ((w >> 1) * 64 + jt * 16 + lo) * 32 + hi * 8);
#pragma unroll
        for (int mt = 0; mt < 2; ++mt)
#pragma unroll
            for (int jt = 0; jt < 4; ++jt)
                acc[mt][jt] = mfma16(af[mt], bfr[jt], acc[mt][jt]);
        __syncthreads();
    }

#pragma unroll
    for (int mt = 0; mt < 2; ++mt)
#pragma unroll
        for (int r = 0; r < 4; ++r) {
            const int j = j0 + (w & 1) * 32 + mt * 16 + hi * 4 + r;
            const float bias = bp[j];
            float* op = out + ((size_t)(b * C_ + j)) * N_ + (n0 & 1023) + (w >> 1) * 64 + lo;
#pragma unroll
            for (int jt = 0; jt < 4; ++jt)
                op[jt * 16] = acc[mt][jt][r] + bias;
        }
}

extern "C" void kernel_launch(void* const* d_in, const int* in_sizes, int n_in,
                              void* d_out, int out_size, void* d_ws, size_t ws_size,
                              hipStream_t stream) {
    const float* x  = (const float*)d_in[0];
    const float* Wq = (const float*)d_in[1];
    const float* bq = (const float*)d_in[2];
    const float* Wp = (const float*)d_in[3];
    const float* bp = (const float*)d_in[4];
    float* out = (float*)d_out;

    const size_t headElems = (size_t)B_ * NH_ * N_ * HD_;
    bf16* xb  = (bf16*)d_ws;
    bf16* Wqb = xb + (size_t)B_ * N_ * C_;
    bf16* Wpb = Wqb + (size_t)C3_ * C_;
    bf16* Qb  = Wpb + (size_t)C_ * C_;
    bf16* Kb  = Qb + headElems;
    bf16* Vt  = Kb + headElems;
    bf16* aob = Vt + headElems;

    prep<<<dim3(4096 + 1024), dim3(256), 0, stream>>>(x, Wq, Wp, xb, Wqb, Wpb);

    qkv_mfma<<<dim3(C3_ / 128, (B_ * N_) / 128), dim3(256), 0, stream>>>(xb, Wqb, bq, Qb, Kb, Vt);
    attn_mfma<<<dim3(8 * 64), dim3(256), 0, stream>>>(Qb, Kb, Vt, aob);
    proj_mfma<<<dim3(C_ / 64, (B_ * N_) / 128), dim3(256), 0, stream>>>(aob, Wpb, bp, out);
}